// Round 1
// baseline (438.908 us; speedup 1.0000x reference)
//
#include <hip/hip_runtime.h>
#include <math.h>

#define B 32
#define P1 778
#define NF 1538
#define P2 3000
#define PARAM_DIM 61
#define LATENT 64

// ws layout (float offsets)
#define NRM_OFF   0                        // 2*B*P1 float4 normals
#define NRM_SZ    (2*B*P1*4)
#define O2H_OFF   (NRM_OFF + NRM_SZ)       // 2*B*P2 signed dists
#define O2H_SZ    (2*B*P2)
#define H2O_OFF   (O2H_OFF + O2H_SZ)       // 2*B*P1 uint bits of min d2
#define H2O_SZ    (2*B*P1)
#define ACC_OFF   (H2O_OFF + H2O_SZ)       // 5 accumulators

// ---------------- Kernel 1: per-batch vertex normals (both sets) -------------
__global__ void knormals(const float* __restrict__ recon_xyz,
                         const float* __restrict__ hand_xyz,
                         const int* __restrict__ faces,
                         float* __restrict__ ws) {
  const int b = blockIdx.x;
  const int set = blockIdx.y;
  const float* verts = (set == 0 ? recon_xyz : hand_xyz) + b * P1 * 3;
  const int* f = faces + b * NF * 3;
  __shared__ float4 sv[P1];
  __shared__ float sn[P1 * 3];
  const int tid = threadIdx.x;
  for (int i = tid; i < P1; i += 256)
    sv[i] = make_float4(verts[3*i], verts[3*i+1], verts[3*i+2], 0.f);
  for (int i = tid; i < P1 * 3; i += 256) sn[i] = 0.f;
  __syncthreads();
  for (int k = tid; k < NF; k += 256) {
    int i0 = f[3*k], i1 = f[3*k+1], i2 = f[3*k+2];
    float4 v0 = sv[i0], v1 = sv[i1], v2 = sv[i2];
    float e0x = v1.x - v0.x, e0y = v1.y - v0.y, e0z = v1.z - v0.z;
    float e1x = v2.x - v0.x, e1y = v2.y - v0.y, e1z = v2.z - v0.z;
    float fx = e0y * e1z - e0z * e1y;
    float fy = e0z * e1x - e0x * e1z;
    float fz = e0x * e1y - e0y * e1x;
    atomicAdd(&sn[3*i0+0], fx); atomicAdd(&sn[3*i0+1], fy); atomicAdd(&sn[3*i0+2], fz);
    atomicAdd(&sn[3*i1+0], fx); atomicAdd(&sn[3*i1+1], fy); atomicAdd(&sn[3*i1+2], fz);
    atomicAdd(&sn[3*i2+0], fx); atomicAdd(&sn[3*i2+1], fy); atomicAdd(&sn[3*i2+2], fz);
  }
  __syncthreads();
  float4* nout = (float4*)(ws + NRM_OFF) + (size_t)(set * B + b) * P1;
  for (int p = tid; p < P1; p += 256) {
    float nx = sn[3*p], ny = sn[3*p+1], nz = sn[3*p+2];
    float nn = sqrtf(nx*nx + ny*ny + nz*nz);
    float inv = 1.f / fmaxf(nn, 1e-6f);
    nout[p] = make_float4(nx*inv, ny*inv, nz*inv, 0.f);
  }
}

// ---------------- Kernel 2: per-obj argmin over hand pts -> signed o2h -------
#define K2_CHUNK 512
__global__ void ko2h(const float* __restrict__ recon_xyz,
                     const float* __restrict__ hand_xyz,
                     const float* __restrict__ obj,
                     float* __restrict__ ws) {
  const int chunk = blockIdx.x, b = blockIdx.y, set = blockIdx.z;
  const float* verts = (set == 0 ? recon_xyz : hand_xyz) + b * P1 * 3;
  const float4* nrm = (const float4*)(ws + NRM_OFF) + (size_t)(set * B + b) * P1;
  __shared__ float4 shp[P1];
  __shared__ float4 snr[P1];
  const int tid = threadIdx.x;
  for (int i = tid; i < P1; i += 256) {
    shp[i] = make_float4(verts[3*i], verts[3*i+1], verts[3*i+2], 0.f);
    snr[i] = nrm[i];
  }
  __syncthreads();
  float* o2h = ws + O2H_OFF + (size_t)(set * B + b) * P2;
  const float* op = obj + (size_t)b * P2 * 3;
  for (int qq = 0; qq < 2; ++qq) {
    int q = chunk * K2_CHUNK + qq * 256 + tid;
    if (q < P2) {
      float px = op[3*q], py = op[3*q+1], pz = op[3*q+2];
      float best = 3.0e38f;
      int bi = 0;
      #pragma unroll 2
      for (int p = 0; p < P1; ++p) {
        float4 h = shp[p];
        float dx = h.x - px, dy = h.y - py, dz = h.z - pz;
        float d2 = fmaf(dx, dx, fmaf(dy, dy, dz * dz));
        bool c = d2 < best;
        best = c ? d2 : best;
        bi = c ? p : bi;
      }
      float4 hb = shp[bi];
      float4 nb = snr[bi];
      float vx = px - hb.x, vy = py - hb.y, vz = pz - hb.z;
      float dt = nb.x * vx + nb.y * vy + nb.z * vz;
      float s = (dt > 0.f) ? 1.f : ((dt < 0.f) ? -1.f : 0.f);
      o2h[q] = sqrtf(best) * s;
    }
  }
}

// ---------------- Kernel 3: per-hand min over obj chunks ---------------------
#define K3_CHUNK 1000
__global__ void kh2o(const float* __restrict__ recon_xyz,
                     const float* __restrict__ hand_xyz,
                     const float* __restrict__ obj,
                     float* __restrict__ ws) {
  const int chunk = blockIdx.x, b = blockIdx.y, set = blockIdx.z;
  const float* verts = (set == 0 ? recon_xyz : hand_xyz) + b * P1 * 3;
  const float* op = obj + (size_t)(b * P2 + chunk * K3_CHUNK) * 3;
  __shared__ float4 so[K3_CHUNK];
  const int tid = threadIdx.x;
  for (int i = tid; i < K3_CHUNK; i += 256)
    so[i] = make_float4(op[3*i], op[3*i+1], op[3*i+2], 0.f);
  __syncthreads();
  unsigned* bits = (unsigned*)(ws + H2O_OFF) + (size_t)(set * B + b) * P1;
  for (int p = tid; p < P1; p += 256) {
    float px = verts[3*p], py = verts[3*p+1], pz = verts[3*p+2];
    float best = 3.0e38f;
    #pragma unroll 4
    for (int q = 0; q < K3_CHUNK; ++q) {
      float4 o = so[q];
      float dx = o.x - px, dy = o.y - py, dz = o.z - pz;
      float d2 = fmaf(dx, dx, fmaf(dy, dy, dz * dz));
      best = fminf(best, d2);
    }
    atomicMin(&bits[p], __float_as_uint(best));
  }
}

// ---------------- Kernel 4: param/recon/KLD partial sums ---------------------
__global__ void kred1(const float* __restrict__ recon_x, const float* __restrict__ x,
                      const float* __restrict__ mu, const float* __restrict__ logvar,
                      const float* __restrict__ recon_xyz, const float* __restrict__ hand_xyz,
                      float* __restrict__ ws) {
  float* acc = ws + ACC_OFF;
  const int gtid = blockIdx.x * blockDim.x + threadIdx.x;
  const int stride = gridDim.x * blockDim.x;
  float sp = 0.f, sr = 0.f, sk = 0.f;
  for (int i = gtid; i < B * PARAM_DIM; i += stride) { float d = recon_x[i] - x[i]; sp += d * d; }
  for (int i = gtid; i < B * P1 * 3; i += stride)    { float d = recon_xyz[i] - hand_xyz[i]; sr += d * d; }
  for (int i = gtid; i < B * LATENT; i += stride)    { float lv = logvar[i], m = mu[i]; sk += 1.f + lv - m * m - expf(lv); }
  for (int off = 32; off > 0; off >>= 1) {
    sp += __shfl_down(sp, off, 64);
    sr += __shfl_down(sr, off, 64);
    sk += __shfl_down(sk, off, 64);
  }
  if ((threadIdx.x & 63) == 0) {
    atomicAdd(&acc[0], sp);
    atomicAdd(&acc[1], sr);
    atomicAdd(&acc[2], sk);
  }
}

// ---------------- Kernel 5: loss_h / loss_o partial sums ---------------------
__global__ void kred2(const float* __restrict__ vw, float* __restrict__ ws) {
  const float* o2h = ws + O2H_OFF;
  const unsigned* bits = (const unsigned*)(ws + H2O_OFF);
  float* acc = ws + ACC_OFF;
  const int gtid = blockIdx.x * blockDim.x + threadIdx.x;
  const int stride = gridDim.x * blockDim.x;
  float sh = 0.f, so = 0.f;
  for (int i = gtid; i < B * P1; i += stride) {
    float a  = sqrtf(__uint_as_float(bits[i]));
    float ag = sqrtf(__uint_as_float(bits[B * P1 + i]));
    sh += fabsf(a - ag) * powf(vw[i % P1], 0.4f);
  }
  for (int i = gtid; i < B * P2; i += stride) {
    float o  = o2h[i];
    float og = o2h[B * P2 + i];
    bool wdist = (og < 0.01f) && (og > -0.005f);
    float w = (o < 0.f) ? 1.5f : (wdist ? 1.f : 0.1f);
    so += fabsf(o - og) * w;
  }
  for (int off = 32; off > 0; off >>= 1) {
    sh += __shfl_down(sh, off, 64);
    so += __shfl_down(so, off, 64);
  }
  if ((threadIdx.x & 63) == 0) {
    atomicAdd(&acc[3], sh);
    atomicAdd(&acc[4], so);
  }
}

// ---------------- Kernel 6: finalize -----------------------------------------
__global__ void kfin(const float* __restrict__ ws, float* __restrict__ out) {
  const float* acc = ws + ACC_OFF;
  float param_loss = acc[0] / (float)B;
  float recon_loss = acc[1] / (float)B;
  float KLD = -0.5f * acc[2] / (float)B;
  float cvae = recon_loss + KLD;
  float loss_h = 35.f * (1.f - 0.005f) * acc[3] / (float)(B * P1);
  float loss_o = 30.f * (1.f - 0.005f) * acc[4] / (float)(B * P2);
  float ho = loss_h + loss_o;
  float loss = cvae + 0.1f * param_loss + 10.f * ho;
  out[0] = loss;
  out[1] = param_loss;
  out[2] = ho;
  out[3] = recon_loss;
  out[4] = KLD;
}

extern "C" void kernel_launch(void* const* d_in, const int* in_sizes, int n_in,
                              void* d_out, int out_size, void* d_ws, size_t ws_size,
                              hipStream_t stream) {
  const float* recon_x   = (const float*)d_in[0];
  const float* x         = (const float*)d_in[1];
  const float* mu        = (const float*)d_in[2];
  const float* logvar    = (const float*)d_in[3];
  const float* recon_xyz = (const float*)d_in[4];
  const float* hand_xyz  = (const float*)d_in[5];
  const int*   faces     = (const int*)d_in[6];
  const float* obj       = (const float*)d_in[7];
  const float* vw        = (const float*)d_in[8];
  float* ws = (float*)d_ws;
  float* out = (float*)d_out;

  // init: h2o min-bits to large positive float (0x7F7F7F7F), accumulators to 0
  hipMemsetAsync(ws + H2O_OFF, 0x7F, H2O_SZ * sizeof(float), stream);
  hipMemsetAsync(ws + ACC_OFF, 0, 5 * sizeof(float), stream);

  knormals<<<dim3(B, 2), 256, 0, stream>>>(recon_xyz, hand_xyz, faces, ws);
  ko2h<<<dim3(6, B, 2), 256, 0, stream>>>(recon_xyz, hand_xyz, obj, ws);
  kh2o<<<dim3(3, B, 2), 256, 0, stream>>>(recon_xyz, hand_xyz, obj, ws);
  kred1<<<dim3(32), 256, 0, stream>>>(recon_x, x, mu, logvar, recon_xyz, hand_xyz, ws);
  kred2<<<dim3(32), 256, 0, stream>>>(vw, ws);
  kfin<<<1, 1, 0, stream>>>(ws, out);
}

// Round 2
// 211.311 us; speedup vs baseline: 2.0771x; 2.0771x over previous
//
#include <hip/hip_runtime.h>
#include <math.h>

#define B 32
#define P1 778
#define NF 1538
#define P2 3000
#define PARAM_DIM 61
#define LATENT 64

// ws layout (float offsets)
#define NRM_OFF   0                        // 2*B*P1 float4 normals
#define NRM_SZ    (2*B*P1*4)
#define O2H_OFF   (NRM_OFF + NRM_SZ)       // 2*B*P2 signed dists
#define O2H_SZ    (2*B*P2)
#define H2O_OFF   (O2H_OFF + O2H_SZ)       // 2*B*P1 uint bits of min d2
#define H2O_SZ    (2*B*P1)
#define ACC_OFF   (H2O_OFF + H2O_SZ)       // 5 accumulators

// ---------------- Kernel 1: per-batch vertex normals (both sets) -------------
__global__ void knormals(const float* __restrict__ recon_xyz,
                         const float* __restrict__ hand_xyz,
                         const int* __restrict__ faces,
                         float* __restrict__ ws) {
  const int b = blockIdx.x;
  const int set = blockIdx.y;
  const float* verts = (set == 0 ? recon_xyz : hand_xyz) + b * P1 * 3;
  const int* f = faces + b * NF * 3;
  __shared__ float4 sv[P1];
  __shared__ float sn[P1 * 3];
  const int tid = threadIdx.x;
  for (int i = tid; i < P1; i += 256)
    sv[i] = make_float4(verts[3*i], verts[3*i+1], verts[3*i+2], 0.f);
  for (int i = tid; i < P1 * 3; i += 256) sn[i] = 0.f;
  __syncthreads();
  for (int k = tid; k < NF; k += 256) {
    int i0 = f[3*k], i1 = f[3*k+1], i2 = f[3*k+2];
    float4 v0 = sv[i0], v1 = sv[i1], v2 = sv[i2];
    float e0x = v1.x - v0.x, e0y = v1.y - v0.y, e0z = v1.z - v0.z;
    float e1x = v2.x - v0.x, e1y = v2.y - v0.y, e1z = v2.z - v0.z;
    float fx = e0y * e1z - e0z * e1y;
    float fy = e0z * e1x - e0x * e1z;
    float fz = e0x * e1y - e0y * e1x;
    atomicAdd(&sn[3*i0+0], fx); atomicAdd(&sn[3*i0+1], fy); atomicAdd(&sn[3*i0+2], fz);
    atomicAdd(&sn[3*i1+0], fx); atomicAdd(&sn[3*i1+1], fy); atomicAdd(&sn[3*i1+2], fz);
    atomicAdd(&sn[3*i2+0], fx); atomicAdd(&sn[3*i2+1], fy); atomicAdd(&sn[3*i2+2], fz);
  }
  __syncthreads();
  float4* nout = (float4*)(ws + NRM_OFF) + (size_t)(set * B + b) * P1;
  for (int p = tid; p < P1; p += 256) {
    float nx = sn[3*p], ny = sn[3*p+1], nz = sn[3*p+2];
    float nn = sqrtf(nx*nx + ny*ny + nz*nz);
    float inv = 1.f / fmaxf(nn, 1e-6f);
    nout[p] = make_float4(nx*inv, ny*inv, nz*inv, 0.f);
  }
}

// ---------------- Kernel 2: per-obj argmin over hand pts -> signed o2h -------
// grid (6, B, 2), 256 threads; each thread owns 2 obj points, single pass
// over all 778 hand pts held in LDS (broadcast reads).
#define K2_OBJ 512
__global__ void ko2h(const float* __restrict__ recon_xyz,
                     const float* __restrict__ hand_xyz,
                     const float* __restrict__ obj,
                     float* __restrict__ ws) {
  const int chunk = blockIdx.x, b = blockIdx.y, set = blockIdx.z;
  const float* verts = (set == 0 ? recon_xyz : hand_xyz) + b * P1 * 3;
  const float4* nrm = (const float4*)(ws + NRM_OFF) + (size_t)(set * B + b) * P1;
  __shared__ float4 shp[P1];
  __shared__ float4 snr[P1];
  const int tid = threadIdx.x;
  for (int i = tid; i < P1; i += 256) {
    shp[i] = make_float4(verts[3*i], verts[3*i+1], verts[3*i+2], 0.f);
    snr[i] = nrm[i];
  }
  __syncthreads();
  float* o2h = ws + O2H_OFF + (size_t)(set * B + b) * P2;
  const float* op = obj + (size_t)b * P2 * 3;

  const int q0 = chunk * K2_OBJ + tid;
  const int q1 = q0 + 256;
  const bool v0 = q0 < P2, v1 = q1 < P2;
  float p0x = 0.f, p0y = 0.f, p0z = 0.f, p1x = 0.f, p1y = 0.f, p1z = 0.f;
  if (v0) { p0x = op[3*q0]; p0y = op[3*q0+1]; p0z = op[3*q0+2]; }
  if (v1) { p1x = op[3*q1]; p1y = op[3*q1+1]; p1z = op[3*q1+2]; }

  float best0 = 3.0e38f, best1 = 3.0e38f;
  int bi0 = 0, bi1 = 0;
  #pragma unroll 2
  for (int p = 0; p < P1; ++p) {
    float4 h = shp[p];
    float dx0 = h.x - p0x, dy0 = h.y - p0y, dz0 = h.z - p0z;
    float d20 = fmaf(dx0, dx0, fmaf(dy0, dy0, dz0 * dz0));
    float dx1 = h.x - p1x, dy1 = h.y - p1y, dz1 = h.z - p1z;
    float d21 = fmaf(dx1, dx1, fmaf(dy1, dy1, dz1 * dz1));
    bool c0 = d20 < best0;
    best0 = c0 ? d20 : best0;
    bi0 = c0 ? p : bi0;
    bool c1 = d21 < best1;
    best1 = c1 ? d21 : best1;
    bi1 = c1 ? p : bi1;
  }
  if (v0) {
    float4 hb = shp[bi0], nb = snr[bi0];
    float vx = p0x - hb.x, vy = p0y - hb.y, vz = p0z - hb.z;
    float dt = nb.x * vx + nb.y * vy + nb.z * vz;
    float s = (dt > 0.f) ? 1.f : ((dt < 0.f) ? -1.f : 0.f);
    o2h[q0] = sqrtf(best0) * s;
  }
  if (v1) {
    float4 hb = shp[bi1], nb = snr[bi1];
    float vx = p1x - hb.x, vy = p1y - hb.y, vz = p1z - hb.z;
    float dt = nb.x * vx + nb.y * vy + nb.z * vz;
    float s = (dt > 0.f) ? 1.f : ((dt < 0.f) ? -1.f : 0.f);
    o2h[q1] = sqrtf(best1) * s;
  }
}

// ---------------- Kernel 3: per-hand min over obj chunks ---------------------
// grid (12, B, 2), 256 threads; each thread owns 3 hand points in registers,
// one LDS broadcast read feeds 3 independent min chains. 10-pt tail in wave 0.
#define K3_C 250
__global__ void kh2o(const float* __restrict__ recon_xyz,
                     const float* __restrict__ hand_xyz,
                     const float* __restrict__ obj,
                     float* __restrict__ ws) {
  const int chunk = blockIdx.x, b = blockIdx.y, set = blockIdx.z;
  const float* verts = (set == 0 ? recon_xyz : hand_xyz) + b * P1 * 3;
  const float* op = obj + (size_t)(b * P2 + chunk * K3_C) * 3;
  __shared__ float4 so[K3_C];
  const int tid = threadIdx.x;
  for (int i = tid; i < K3_C; i += 256)
    so[i] = make_float4(op[3*i], op[3*i+1], op[3*i+2], 0.f);
  __syncthreads();
  unsigned* bits = (unsigned*)(ws + H2O_OFF) + (size_t)(set * B + b) * P1;

  const int p0 = tid, p1 = tid + 256, p2 = tid + 512;   // all < 768 < P1
  float ax = verts[3*p0], ay = verts[3*p0+1], az = verts[3*p0+2];
  float bx = verts[3*p1], by = verts[3*p1+1], bz = verts[3*p1+2];
  float cx = verts[3*p2], cy = verts[3*p2+1], cz = verts[3*p2+2];
  float m0 = 3.0e38f, m1 = 3.0e38f, m2 = 3.0e38f;
  #pragma unroll 2
  for (int q = 0; q < K3_C; ++q) {
    float4 o = so[q];
    float dx = o.x - ax, dy = o.y - ay, dz = o.z - az;
    m0 = fminf(m0, fmaf(dx, dx, fmaf(dy, dy, dz * dz)));
    dx = o.x - bx; dy = o.y - by; dz = o.z - bz;
    m1 = fminf(m1, fmaf(dx, dx, fmaf(dy, dy, dz * dz)));
    dx = o.x - cx; dy = o.y - cy; dz = o.z - cz;
    m2 = fminf(m2, fmaf(dx, dx, fmaf(dy, dy, dz * dz)));
  }
  atomicMin(&bits[p0], __float_as_uint(m0));
  atomicMin(&bits[p1], __float_as_uint(m1));
  atomicMin(&bits[p2], __float_as_uint(m2));

  // tail: hand points 768..777 (10 pts), handled by lanes 0..9 of wave 0
  if (tid < P1 - 768) {
    const int p3 = 768 + tid;
    float tx = verts[3*p3], ty = verts[3*p3+1], tz = verts[3*p3+2];
    float m3 = 3.0e38f;
    #pragma unroll 2
    for (int q = 0; q < K3_C; ++q) {
      float4 o = so[q];
      float dx = o.x - tx, dy = o.y - ty, dz = o.z - tz;
      m3 = fminf(m3, fmaf(dx, dx, fmaf(dy, dy, dz * dz)));
    }
    atomicMin(&bits[p3], __float_as_uint(m3));
  }
}

// ---------------- Kernel 4: param/recon/KLD partial sums ---------------------
__global__ void kred1(const float* __restrict__ recon_x, const float* __restrict__ x,
                      const float* __restrict__ mu, const float* __restrict__ logvar,
                      const float* __restrict__ recon_xyz, const float* __restrict__ hand_xyz,
                      float* __restrict__ ws) {
  float* acc = ws + ACC_OFF;
  const int gtid = blockIdx.x * blockDim.x + threadIdx.x;
  const int stride = gridDim.x * blockDim.x;
  float sp = 0.f, sr = 0.f, sk = 0.f;
  for (int i = gtid; i < B * PARAM_DIM; i += stride) { float d = recon_x[i] - x[i]; sp += d * d; }
  for (int i = gtid; i < B * P1 * 3; i += stride)    { float d = recon_xyz[i] - hand_xyz[i]; sr += d * d; }
  for (int i = gtid; i < B * LATENT; i += stride)    { float lv = logvar[i], m = mu[i]; sk += 1.f + lv - m * m - expf(lv); }
  for (int off = 32; off > 0; off >>= 1) {
    sp += __shfl_down(sp, off, 64);
    sr += __shfl_down(sr, off, 64);
    sk += __shfl_down(sk, off, 64);
  }
  if ((threadIdx.x & 63) == 0) {
    atomicAdd(&acc[0], sp);
    atomicAdd(&acc[1], sr);
    atomicAdd(&acc[2], sk);
  }
}

// ---------------- Kernel 5: loss_h / loss_o partial sums ---------------------
__global__ void kred2(const float* __restrict__ vw, float* __restrict__ ws) {
  const float* o2h = ws + O2H_OFF;
  const unsigned* bits = (const unsigned*)(ws + H2O_OFF);
  float* acc = ws + ACC_OFF;
  const int gtid = blockIdx.x * blockDim.x + threadIdx.x;
  const int stride = gridDim.x * blockDim.x;
  float sh = 0.f, so = 0.f;
  for (int i = gtid; i < B * P1; i += stride) {
    float a  = sqrtf(__uint_as_float(bits[i]));
    float ag = sqrtf(__uint_as_float(bits[B * P1 + i]));
    sh += fabsf(a - ag) * powf(vw[i % P1], 0.4f);
  }
  for (int i = gtid; i < B * P2; i += stride) {
    float o  = o2h[i];
    float og = o2h[B * P2 + i];
    bool wdist = (og < 0.01f) && (og > -0.005f);
    float w = (o < 0.f) ? 1.5f : (wdist ? 1.f : 0.1f);
    so += fabsf(o - og) * w;
  }
  for (int off = 32; off > 0; off >>= 1) {
    sh += __shfl_down(sh, off, 64);
    so += __shfl_down(so, off, 64);
  }
  if ((threadIdx.x & 63) == 0) {
    atomicAdd(&acc[3], sh);
    atomicAdd(&acc[4], so);
  }
}

// ---------------- Kernel 6: finalize -----------------------------------------
__global__ void kfin(const float* __restrict__ ws, float* __restrict__ out) {
  const float* acc = ws + ACC_OFF;
  float param_loss = acc[0] / (float)B;
  float recon_loss = acc[1] / (float)B;
  float KLD = -0.5f * acc[2] / (float)B;
  float cvae = recon_loss + KLD;
  float loss_h = 35.f * (1.f - 0.005f) * acc[3] / (float)(B * P1);
  float loss_o = 30.f * (1.f - 0.005f) * acc[4] / (float)(B * P2);
  float ho = loss_h + loss_o;
  float loss = cvae + 0.1f * param_loss + 10.f * ho;
  out[0] = loss;
  out[1] = param_loss;
  out[2] = ho;
  out[3] = recon_loss;
  out[4] = KLD;
}

extern "C" void kernel_launch(void* const* d_in, const int* in_sizes, int n_in,
                              void* d_out, int out_size, void* d_ws, size_t ws_size,
                              hipStream_t stream) {
  const float* recon_x   = (const float*)d_in[0];
  const float* x         = (const float*)d_in[1];
  const float* mu        = (const float*)d_in[2];
  const float* logvar    = (const float*)d_in[3];
  const float* recon_xyz = (const float*)d_in[4];
  const float* hand_xyz  = (const float*)d_in[5];
  const int*   faces     = (const int*)d_in[6];
  const float* obj       = (const float*)d_in[7];
  const float* vw        = (const float*)d_in[8];
  float* ws = (float*)d_ws;
  float* out = (float*)d_out;

  hipMemsetAsync(ws + H2O_OFF, 0x7F, H2O_SZ * sizeof(float), stream);
  hipMemsetAsync(ws + ACC_OFF, 0, 5 * sizeof(float), stream);

  knormals<<<dim3(B, 2), 256, 0, stream>>>(recon_xyz, hand_xyz, faces, ws);
  kh2o<<<dim3(12, B, 2), 256, 0, stream>>>(recon_xyz, hand_xyz, obj, ws);
  ko2h<<<dim3(6, B, 2), 256, 0, stream>>>(recon_xyz, hand_xyz, obj, ws);
  kred1<<<dim3(32), 256, 0, stream>>>(recon_x, x, mu, logvar, recon_xyz, hand_xyz, ws);
  kred2<<<dim3(32), 256, 0, stream>>>(vw, ws);
  kfin<<<1, 1, 0, stream>>>(ws, out);
}

// Round 3
// 171.607 us; speedup vs baseline: 2.5576x; 1.2314x over previous
//
#include <hip/hip_runtime.h>
#include <math.h>

#define B 32
#define P1 778
#define NF 1538
#define P2 3000
#define PARAM_DIM 61
#define LATENT 64

#define NCH_H2O 4
#define CH_H2O 750            // 4*750 = 3000
#define NCH_O2H 6             // 6*512 = 3072 >= 3000
#define RED1_BLKS 16
#define RED2_BLKS 384

// megakernel role block ranges
#define NB_O2H (NCH_O2H * 64)     // 384
#define NB_H2O (NCH_H2O * 64)     // 256
#define NB_NRM 64
#define NB_TOT (NB_O2H + NB_H2O + NB_NRM + RED1_BLKS)   // 720

// ws layout (float offsets)
#define NRM_OFF 0                          // 2*B*P1 float4
#define NRM_SZ  (2*B*P1*4)
#define KEY_OFF (NRM_OFF + NRM_SZ)         // 2*B*P2 ints (argmin hand index)
#define KEY_SZ  (2*B*P2)
#define HP_OFF  (KEY_OFF + KEY_SZ)         // NCH_H2O*2*B*P1 floats (chunk partial min d2)
#define HP_SZ   (NCH_H2O*2*B*P1)
#define R1_OFF  (HP_OFF + HP_SZ)           // RED1_BLKS*3
#define R2_OFF  (R1_OFF + RED1_BLKS*3)     // RED2_BLKS*2

// ---------------- Megakernel A: all independent work, one dispatch -----------
__global__ __launch_bounds__(256) void kmega(
    const float* __restrict__ recon_x, const float* __restrict__ x,
    const float* __restrict__ mu, const float* __restrict__ logvar,
    const float* __restrict__ recon_xyz, const float* __restrict__ hand_xyz,
    const int* __restrict__ faces, const float* __restrict__ obj,
    float* __restrict__ ws) {
  __shared__ float smem[5446];   // max role need: norm = 778*4 + 778*3 = 5446
  const int tid = threadIdx.x;
  const int bid = blockIdx.x;

  if (bid < NB_O2H) {
    // ---- role: per-obj argmin over hand pts (store bi only) ----
    const int chunk = bid >> 6, r = bid & 63, set = r >> 5, b = r & 31;
    const float* verts = (set == 0 ? recon_xyz : hand_xyz) + b * P1 * 3;
    float4* s4 = (float4*)smem;
    for (int i = tid; i < P1; i += 256) {
      float vx = verts[3*i], vy = verts[3*i+1], vz = verts[3*i+2];
      s4[i] = make_float4(vx, vy, vz, vx*vx + vy*vy + vz*vz);  // w = |h|^2
    }
    __syncthreads();
    const float* op = obj + (size_t)b * P2 * 3;
    const int q0 = chunk * 512 + tid;           // always < 3000 for chunk<=5,tid<256? max 2815 ok
    const int q1 = q0 + 256;
    float a0 = 0.f, b0 = 0.f, c0 = 0.f, a1 = 0.f, b1 = 0.f, c1 = 0.f;
    { a0 = -2.f*op[3*q0]; b0 = -2.f*op[3*q0+1]; c0 = -2.f*op[3*q0+2]; }
    if (q1 < P2) { a1 = -2.f*op[3*q1]; b1 = -2.f*op[3*q1+1]; c1 = -2.f*op[3*q1+2]; }
    float best0 = 3.0e38f, best1 = 3.0e38f;
    int bi0 = 0, bi1 = 0;
    #pragma unroll 2
    for (int p = 0; p < P1; ++p) {
      float4 h = s4[p];
      // d2 - |o|^2 = |h|^2 - 2 h.o  (monotone in p for fixed obj)
      float d0 = fmaf(h.x, a0, fmaf(h.y, b0, fmaf(h.z, c0, h.w)));
      float d1 = fmaf(h.x, a1, fmaf(h.y, b1, fmaf(h.z, c1, h.w)));
      bool k0 = d0 < best0; best0 = k0 ? d0 : best0; bi0 = k0 ? p : bi0;
      bool k1 = d1 < best1; best1 = k1 ? d1 : best1; bi1 = k1 ? p : bi1;
    }
    int* keys = (int*)(ws + KEY_OFF) + (size_t)(set * B + b) * P2;
    keys[q0] = bi0;
    if (q1 < P2) keys[q1] = bi1;

  } else if (bid < NB_O2H + NB_H2O) {
    // ---- role: per-hand partial min over one obj chunk (no atomics) ----
    const int t = bid - NB_O2H;
    const int chunk = t >> 6, r = t & 63, set = r >> 5, b = r & 31;
    const float* verts = (set == 0 ? recon_xyz : hand_xyz) + b * P1 * 3;
    const float* op = obj + (size_t)(b * P2 + chunk * CH_H2O) * 3;
    float4* s4 = (float4*)smem;
    for (int i = tid; i < CH_H2O; i += 256) {
      float ox = op[3*i], oy = op[3*i+1], oz = op[3*i+2];
      s4[i] = make_float4(ox, oy, oz, ox*ox + oy*oy + oz*oz);  // w = |o|^2
    }
    __syncthreads();
    float* part = ws + HP_OFF + (size_t)((chunk * 2 + set) * B + b) * P1;
    const int p0 = tid, p1 = tid + 256, p2 = tid + 512;   // all < 768
    float ax = verts[3*p0], ay = verts[3*p0+1], az = verts[3*p0+2];
    float bx = verts[3*p1], by = verts[3*p1+1], bz = verts[3*p1+2];
    float cx = verts[3*p2], cy = verts[3*p2+1], cz = verts[3*p2+2];
    float h2a = ax*ax+ay*ay+az*az, h2b = bx*bx+by*by+bz*bz, h2c = cx*cx+cy*cy+cz*cz;
    float nax = -2.f*ax, nay = -2.f*ay, naz = -2.f*az;
    float nbx = -2.f*bx, nby = -2.f*by, nbz = -2.f*bz;
    float ncx = -2.f*cx, ncy = -2.f*cy, ncz = -2.f*cz;
    float m0 = 3.0e38f, m1 = 3.0e38f, m2 = 3.0e38f;
    #pragma unroll 2
    for (int q = 0; q < CH_H2O; ++q) {
      float4 o = s4[q];
      // d2 - |h|^2 = |o|^2 - 2 h.o
      m0 = fminf(m0, fmaf(o.x, nax, fmaf(o.y, nay, fmaf(o.z, naz, o.w))));
      m1 = fminf(m1, fmaf(o.x, nbx, fmaf(o.y, nby, fmaf(o.z, nbz, o.w))));
      m2 = fminf(m2, fmaf(o.x, ncx, fmaf(o.y, ncy, fmaf(o.z, ncz, o.w))));
    }
    part[p0] = m0 + h2a;
    part[p1] = m1 + h2b;
    part[p2] = m2 + h2c;
    if (tid < P1 - 768) {   // tail hand pts 768..777
      const int p3 = 768 + tid;
      float tx = verts[3*p3], ty = verts[3*p3+1], tz = verts[3*p3+2];
      float h2t = tx*tx+ty*ty+tz*tz;
      float ntx = -2.f*tx, nty = -2.f*ty, ntz = -2.f*tz;
      float m3 = 3.0e38f;
      for (int q = 0; q < CH_H2O; ++q) {
        float4 o = s4[q];
        m3 = fminf(m3, fmaf(o.x, ntx, fmaf(o.y, nty, fmaf(o.z, ntz, o.w))));
      }
      part[p3] = m3 + h2t;
    }

  } else if (bid < NB_O2H + NB_H2O + NB_NRM) {
    // ---- role: vertex normals ----
    const int r = bid - NB_O2H - NB_H2O, set = r >> 5, b = r & 31;
    const float* verts = (set == 0 ? recon_xyz : hand_xyz) + b * P1 * 3;
    const int* f = faces + b * NF * 3;
    float4* sv = (float4*)smem;           // 778 float4
    float* sn = smem + P1 * 4;            // 778*3 floats
    for (int i = tid; i < P1; i += 256)
      sv[i] = make_float4(verts[3*i], verts[3*i+1], verts[3*i+2], 0.f);
    for (int i = tid; i < P1 * 3; i += 256) sn[i] = 0.f;
    __syncthreads();
    for (int k = tid; k < NF; k += 256) {
      int i0 = f[3*k], i1 = f[3*k+1], i2 = f[3*k+2];
      float4 v0 = sv[i0], v1 = sv[i1], v2 = sv[i2];
      float e0x = v1.x - v0.x, e0y = v1.y - v0.y, e0z = v1.z - v0.z;
      float e1x = v2.x - v0.x, e1y = v2.y - v0.y, e1z = v2.z - v0.z;
      float fx = e0y * e1z - e0z * e1y;
      float fy = e0z * e1x - e0x * e1z;
      float fz = e0x * e1y - e0y * e1x;
      atomicAdd(&sn[3*i0+0], fx); atomicAdd(&sn[3*i0+1], fy); atomicAdd(&sn[3*i0+2], fz);
      atomicAdd(&sn[3*i1+0], fx); atomicAdd(&sn[3*i1+1], fy); atomicAdd(&sn[3*i1+2], fz);
      atomicAdd(&sn[3*i2+0], fx); atomicAdd(&sn[3*i2+1], fy); atomicAdd(&sn[3*i2+2], fz);
    }
    __syncthreads();
    float4* nout = (float4*)(ws + NRM_OFF) + (size_t)(set * B + b) * P1;
    for (int p = tid; p < P1; p += 256) {
      float nx = sn[3*p], ny = sn[3*p+1], nz = sn[3*p+2];
      float nn = sqrtf(nx*nx + ny*ny + nz*nz);
      float inv = 1.f / fmaxf(nn, 1e-6f);
      nout[p] = make_float4(nx*inv, ny*inv, nz*inv, 0.f);
    }

  } else {
    // ---- role: param/recon/KLD partial sums (no atomics) ----
    const int blk = bid - NB_O2H - NB_H2O - NB_NRM;
    const int gtid = blk * 256 + tid, stride = RED1_BLKS * 256;
    float sp = 0.f, sr = 0.f, sk = 0.f;
    for (int i = gtid; i < B * PARAM_DIM; i += stride) { float d = recon_x[i] - x[i]; sp += d * d; }
    for (int i = gtid; i < B * P1 * 3; i += stride)    { float d = recon_xyz[i] - hand_xyz[i]; sr += d * d; }
    for (int i = gtid; i < B * LATENT; i += stride)    { float lv = logvar[i], m = mu[i]; sk += 1.f + lv - m * m - expf(lv); }
    for (int off = 32; off > 0; off >>= 1) {
      sp += __shfl_down(sp, off, 64);
      sr += __shfl_down(sr, off, 64);
      sk += __shfl_down(sk, off, 64);
    }
    const int wv = tid >> 6;
    if ((tid & 63) == 0) { smem[wv*3] = sp; smem[wv*3+1] = sr; smem[wv*3+2] = sk; }
    __syncthreads();
    if (tid == 0) {
      float a = 0.f, bb = 0.f, c = 0.f;
      for (int w = 0; w < 4; ++w) { a += smem[w*3]; bb += smem[w*3+1]; c += smem[w*3+2]; }
      ws[R1_OFF + blk*3+0] = a; ws[R1_OFF + blk*3+1] = bb; ws[R1_OFF + blk*3+2] = c;
    }
  }
}

// ---------------- Kernel B: signs + weighted sums (per-block partials) -------
__global__ __launch_bounds__(256) void kred2(
    const float* __restrict__ recon_xyz, const float* __restrict__ hand_xyz,
    const float* __restrict__ obj, const float* __restrict__ vw,
    float* __restrict__ ws) {
  __shared__ float smem[8];
  const int gtid = blockIdx.x * 256 + threadIdx.x;
  const int stride = RED2_BLKS * 256;
  const int* keys = (const int*)(ws + KEY_OFF);
  const float4* nrm = (const float4*)(ws + NRM_OFF);
  float sh = 0.f, so = 0.f;
  // o-part: signed o2h for both sets, weighted |o - og|
  for (int i = gtid; i < B * P2; i += stride) {
    const int b = i / P2;
    const float* op = obj + (size_t)i * 3;
    float px = op[0], py = op[1], pz = op[2];
    float os[2];
    #pragma unroll
    for (int s = 0; s < 2; ++s) {
      int bi = keys[(size_t)s * B * P2 + i];
      const float* verts = (s == 0 ? recon_xyz : hand_xyz) + (size_t)(b * P1 + bi) * 3;
      float dx = px - verts[0], dy = py - verts[1], dz = pz - verts[2];
      float d2 = fmaf(dx, dx, fmaf(dy, dy, dz * dz));
      float4 nb = nrm[(size_t)(s * B + b) * P1 + bi];
      float dt = nb.x * dx + nb.y * dy + nb.z * dz;
      float sg = (dt > 0.f) ? 1.f : ((dt < 0.f) ? -1.f : 0.f);
      os[s] = sqrtf(d2) * sg;
    }
    bool wdist = (os[1] < 0.01f) && (os[1] > -0.005f);
    float w = (os[0] < 0.f) ? 1.5f : (wdist ? 1.f : 0.1f);
    so += fabsf(os[0] - os[1]) * w;
  }
  // h-part: min over chunks, |a - ag| * vw^0.4
  for (int i = gtid; i < B * P1; i += stride) {
    const int p = i % P1;
    float m0 = 3.0e38f, m1 = 3.0e38f;
    #pragma unroll
    for (int c = 0; c < NCH_H2O; ++c) {
      m0 = fminf(m0, ws[HP_OFF + (size_t)(c*2+0) * B * P1 + i]);
      m1 = fminf(m1, ws[HP_OFF + (size_t)(c*2+1) * B * P1 + i]);
    }
    m0 = fmaxf(m0, 0.f); m1 = fmaxf(m1, 0.f);
    sh += fabsf(sqrtf(m0) - sqrtf(m1)) * powf(vw[p], 0.4f);
  }
  for (int off = 32; off > 0; off >>= 1) {
    sh += __shfl_down(sh, off, 64);
    so += __shfl_down(so, off, 64);
  }
  const int wv = threadIdx.x >> 6;
  if ((threadIdx.x & 63) == 0) { smem[wv*2] = sh; smem[wv*2+1] = so; }
  __syncthreads();
  if (threadIdx.x == 0) {
    float a = 0.f, b = 0.f;
    for (int w = 0; w < 4; ++w) { a += smem[w*2]; b += smem[w*2+1]; }
    ws[R2_OFF + blockIdx.x*2+0] = a;
    ws[R2_OFF + blockIdx.x*2+1] = b;
  }
}

// ---------------- Kernel C: finalize (single wave) ---------------------------
__global__ void kfin(const float* __restrict__ ws, float* __restrict__ out) {
  const int lane = threadIdx.x;
  float sp = 0.f, sr = 0.f, sk = 0.f, sh = 0.f, so = 0.f;
  for (int i = lane; i < RED1_BLKS; i += 64) {
    sp += ws[R1_OFF + i*3+0]; sr += ws[R1_OFF + i*3+1]; sk += ws[R1_OFF + i*3+2];
  }
  for (int i = lane; i < RED2_BLKS; i += 64) {
    sh += ws[R2_OFF + i*2+0]; so += ws[R2_OFF + i*2+1];
  }
  for (int off = 32; off > 0; off >>= 1) {
    sp += __shfl_down(sp, off, 64);
    sr += __shfl_down(sr, off, 64);
    sk += __shfl_down(sk, off, 64);
    sh += __shfl_down(sh, off, 64);
    so += __shfl_down(so, off, 64);
  }
  if (lane == 0) {
    float param_loss = sp / (float)B;
    float recon_loss = sr / (float)B;
    float KLD = -0.5f * sk / (float)B;
    float cvae = recon_loss + KLD;
    float loss_h = 35.f * (1.f - 0.005f) * sh / (float)(B * P1);
    float loss_o = 30.f * (1.f - 0.005f) * so / (float)(B * P2);
    float ho = loss_h + loss_o;
    out[0] = cvae + 0.1f * param_loss + 10.f * ho;
    out[1] = param_loss;
    out[2] = ho;
    out[3] = recon_loss;
    out[4] = KLD;
  }
}

extern "C" void kernel_launch(void* const* d_in, const int* in_sizes, int n_in,
                              void* d_out, int out_size, void* d_ws, size_t ws_size,
                              hipStream_t stream) {
  const float* recon_x   = (const float*)d_in[0];
  const float* x         = (const float*)d_in[1];
  const float* mu        = (const float*)d_in[2];
  const float* logvar    = (const float*)d_in[3];
  const float* recon_xyz = (const float*)d_in[4];
  const float* hand_xyz  = (const float*)d_in[5];
  const int*   faces     = (const int*)d_in[6];
  const float* obj       = (const float*)d_in[7];
  const float* vw        = (const float*)d_in[8];
  float* ws = (float*)d_ws;
  float* out = (float*)d_out;

  kmega<<<dim3(NB_TOT), 256, 0, stream>>>(recon_x, x, mu, logvar,
                                          recon_xyz, hand_xyz, faces, obj, ws);
  kred2<<<dim3(RED2_BLKS), 256, 0, stream>>>(recon_xyz, hand_xyz, obj, vw, ws);
  kfin<<<1, 64, 0, stream>>>(ws, out);
}

// Round 4
// 157.135 us; speedup vs baseline: 2.7932x; 1.0921x over previous
//
#include <hip/hip_runtime.h>
#include <math.h>

#define B 32
#define P1 778
#define NF 1538
#define P2 3000
#define PARAM_DIM 61
#define LATENT 64

#define NCH_O2H 12            // 12*256 = 3072 >= 3000
#define NCH_H2O 8
#define CH_H2O 375            // 8*375 = 3000
#define RED1_BLKS 16
#define RED2_BLKS 384

// megakernel role block ranges
#define NB_O2H (NCH_O2H * 64)     // 768
#define NB_H2O (NCH_H2O * 64)     // 512
#define NB_NRM 64
#define NB_TOT (NB_O2H + NB_H2O + NB_NRM + RED1_BLKS)   // 1360

// ws layout (float offsets)
#define NRM_OFF 0                          // 2*B*P1 float4
#define NRM_SZ  (2*B*P1*4)
#define KEY_OFF (NRM_OFF + NRM_SZ)         // 2*B*P2 ints (argmin hand index)
#define KEY_SZ  (2*B*P2)
#define HP_OFF  (KEY_OFF + KEY_SZ)         // NCH_H2O*2*B*P1 floats (chunk partial min d2)
#define HP_SZ   (NCH_H2O*2*B*P1)
#define R1_OFF  (HP_OFF + HP_SZ)           // RED1_BLKS*3
#define R2_OFF  (R1_OFF + RED1_BLKS*3)     // RED2_BLKS*2

// ---------------- Megakernel A: all independent work, one dispatch -----------
__global__ __launch_bounds__(256) void kmega(
    const float* __restrict__ recon_x, const float* __restrict__ x,
    const float* __restrict__ mu, const float* __restrict__ logvar,
    const float* __restrict__ recon_xyz, const float* __restrict__ hand_xyz,
    const int* __restrict__ faces, const float* __restrict__ obj,
    float* __restrict__ ws) {
  __shared__ float smem[5446];   // max role need: norm = 778*4 + 778*3 = 5446
  const int tid = threadIdx.x;
  const int bid = blockIdx.x;

  if (bid < NB_O2H) {
    // ---- role: per-obj argmin over hand pts, packed-key min (no sel chain) --
    const int chunk = bid >> 6, r = bid & 63, set = r >> 5, b = r & 31;
    const float* verts = (set == 0 ? recon_xyz : hand_xyz) + b * P1 * 3;
    float4* s4 = (float4*)smem;
    for (int i = tid; i < P1; i += 256) {
      float vx = verts[3*i], vy = verts[3*i+1], vz = verts[3*i+2];
      // w = |h|^2 + 64 guarantees d2' = w - 2h.o > 0 for |o|^2 < 64
      s4[i] = make_float4(vx, vy, vz, vx*vx + vy*vy + vz*vz + 64.f);
    }
    __syncthreads();
    const int q = chunk * 256 + tid;
    if (q < P2) {
      const float* op = obj + (size_t)b * P2 * 3;
      float a0 = -2.f*op[3*q], b0 = -2.f*op[3*q+1], c0 = -2.f*op[3*q+2];
      unsigned best = 0xFFFFFFFFu;
      #pragma unroll 4
      for (int p = 0; p < P1; ++p) {
        float4 h = s4[p];
        float d = fmaf(h.x, a0, fmaf(h.y, b0, fmaf(h.z, c0, h.w)));
        unsigned key = (__float_as_uint(d) & 0xFFFFFC00u) | (unsigned)p;
        best = key < best ? key : best;
      }
      int* keys = (int*)(ws + KEY_OFF) + (size_t)(set * B + b) * P2;
      keys[q] = (int)(best & 1023u);
    }

  } else if (bid < NB_O2H + NB_H2O) {
    // ---- role: per-hand partial min over one obj chunk (no atomics) ----
    const int t = bid - NB_O2H;
    const int chunk = t >> 6, r = t & 63, set = r >> 5, b = r & 31;
    const float* verts = (set == 0 ? recon_xyz : hand_xyz) + b * P1 * 3;
    const float* op = obj + (size_t)(b * P2 + chunk * CH_H2O) * 3;
    float4* s4 = (float4*)smem;
    for (int i = tid; i < CH_H2O; i += 256) {
      float ox = op[3*i], oy = op[3*i+1], oz = op[3*i+2];
      s4[i] = make_float4(ox, oy, oz, ox*ox + oy*oy + oz*oz);  // w = |o|^2
    }
    __syncthreads();
    float* part = ws + HP_OFF + (size_t)((chunk * 2 + set) * B + b) * P1;
    const int p0 = tid, p1 = tid + 256, p2 = tid + 512;   // all < 768
    float ax = verts[3*p0], ay = verts[3*p0+1], az = verts[3*p0+2];
    float bx = verts[3*p1], by = verts[3*p1+1], bz = verts[3*p1+2];
    float cx = verts[3*p2], cy = verts[3*p2+1], cz = verts[3*p2+2];
    float h2a = ax*ax+ay*ay+az*az, h2b = bx*bx+by*by+bz*bz, h2c = cx*cx+cy*cy+cz*cz;
    float nax = -2.f*ax, nay = -2.f*ay, naz = -2.f*az;
    float nbx = -2.f*bx, nby = -2.f*by, nbz = -2.f*bz;
    float ncx = -2.f*cx, ncy = -2.f*cy, ncz = -2.f*cz;
    float m0 = 3.0e38f, m1 = 3.0e38f, m2 = 3.0e38f;
    #pragma unroll 4
    for (int q = 0; q < CH_H2O; ++q) {
      float4 o = s4[q];
      // d2 - |h|^2 = |o|^2 - 2 h.o
      m0 = fminf(m0, fmaf(o.x, nax, fmaf(o.y, nay, fmaf(o.z, naz, o.w))));
      m1 = fminf(m1, fmaf(o.x, nbx, fmaf(o.y, nby, fmaf(o.z, nbz, o.w))));
      m2 = fminf(m2, fmaf(o.x, ncx, fmaf(o.y, ncy, fmaf(o.z, ncz, o.w))));
    }
    part[p0] = m0 + h2a;
    part[p1] = m1 + h2b;
    part[p2] = m2 + h2c;
    if (tid < P1 - 768) {   // tail hand pts 768..777
      const int p3 = 768 + tid;
      float tx = verts[3*p3], ty = verts[3*p3+1], tz = verts[3*p3+2];
      float h2t = tx*tx+ty*ty+tz*tz;
      float ntx = -2.f*tx, nty = -2.f*ty, ntz = -2.f*tz;
      float m3 = 3.0e38f;
      for (int q = 0; q < CH_H2O; ++q) {
        float4 o = s4[q];
        m3 = fminf(m3, fmaf(o.x, ntx, fmaf(o.y, nty, fmaf(o.z, ntz, o.w))));
      }
      part[p3] = m3 + h2t;
    }

  } else if (bid < NB_O2H + NB_H2O + NB_NRM) {
    // ---- role: vertex normals ----
    const int r = bid - NB_O2H - NB_H2O, set = r >> 5, b = r & 31;
    const float* verts = (set == 0 ? recon_xyz : hand_xyz) + b * P1 * 3;
    const int* f = faces + b * NF * 3;
    float4* sv = (float4*)smem;           // 778 float4
    float* sn = smem + P1 * 4;            // 778*3 floats
    for (int i = tid; i < P1; i += 256)
      sv[i] = make_float4(verts[3*i], verts[3*i+1], verts[3*i+2], 0.f);
    for (int i = tid; i < P1 * 3; i += 256) sn[i] = 0.f;
    __syncthreads();
    for (int k = tid; k < NF; k += 256) {
      int i0 = f[3*k], i1 = f[3*k+1], i2 = f[3*k+2];
      float4 v0 = sv[i0], v1 = sv[i1], v2 = sv[i2];
      float e0x = v1.x - v0.x, e0y = v1.y - v0.y, e0z = v1.z - v0.z;
      float e1x = v2.x - v0.x, e1y = v2.y - v0.y, e1z = v2.z - v0.z;
      float fx = e0y * e1z - e0z * e1y;
      float fy = e0z * e1x - e0x * e1z;
      float fz = e0x * e1y - e0y * e1x;
      atomicAdd(&sn[3*i0+0], fx); atomicAdd(&sn[3*i0+1], fy); atomicAdd(&sn[3*i0+2], fz);
      atomicAdd(&sn[3*i1+0], fx); atomicAdd(&sn[3*i1+1], fy); atomicAdd(&sn[3*i1+2], fz);
      atomicAdd(&sn[3*i2+0], fx); atomicAdd(&sn[3*i2+1], fy); atomicAdd(&sn[3*i2+2], fz);
    }
    __syncthreads();
    float4* nout = (float4*)(ws + NRM_OFF) + (size_t)(set * B + b) * P1;
    for (int p = tid; p < P1; p += 256) {
      float nx = sn[3*p], ny = sn[3*p+1], nz = sn[3*p+2];
      float nn = sqrtf(nx*nx + ny*ny + nz*nz);
      float inv = 1.f / fmaxf(nn, 1e-6f);
      nout[p] = make_float4(nx*inv, ny*inv, nz*inv, 0.f);
    }

  } else {
    // ---- role: param/recon/KLD partial sums (no atomics) ----
    const int blk = bid - NB_O2H - NB_H2O - NB_NRM;
    const int gtid = blk * 256 + tid, stride = RED1_BLKS * 256;
    float sp = 0.f, sr = 0.f, sk = 0.f;
    for (int i = gtid; i < B * PARAM_DIM; i += stride) { float d = recon_x[i] - x[i]; sp += d * d; }
    for (int i = gtid; i < B * P1 * 3; i += stride)    { float d = recon_xyz[i] - hand_xyz[i]; sr += d * d; }
    for (int i = gtid; i < B * LATENT; i += stride)    { float lv = logvar[i], m = mu[i]; sk += 1.f + lv - m * m - expf(lv); }
    for (int off = 32; off > 0; off >>= 1) {
      sp += __shfl_down(sp, off, 64);
      sr += __shfl_down(sr, off, 64);
      sk += __shfl_down(sk, off, 64);
    }
    const int wv = tid >> 6;
    if ((tid & 63) == 0) { smem[wv*3] = sp; smem[wv*3+1] = sr; smem[wv*3+2] = sk; }
    __syncthreads();
    if (tid == 0) {
      float a = 0.f, bb = 0.f, c = 0.f;
      for (int w = 0; w < 4; ++w) { a += smem[w*3]; bb += smem[w*3+1]; c += smem[w*3+2]; }
      ws[R1_OFF + blk*3+0] = a; ws[R1_OFF + blk*3+1] = bb; ws[R1_OFF + blk*3+2] = c;
    }
  }
}

// ---------------- Kernel B: signs + weighted sums (per-block partials) -------
__global__ __launch_bounds__(256) void kred2(
    const float* __restrict__ recon_xyz, const float* __restrict__ hand_xyz,
    const float* __restrict__ obj, const float* __restrict__ vw,
    float* __restrict__ ws) {
  __shared__ float smem[8];
  const int gtid = blockIdx.x * 256 + threadIdx.x;
  const int stride = RED2_BLKS * 256;
  const int* keys = (const int*)(ws + KEY_OFF);
  const float4* nrm = (const float4*)(ws + NRM_OFF);
  float sh = 0.f, so = 0.f;
  // o-part: signed o2h for both sets, weighted |o - og|
  for (int i = gtid; i < B * P2; i += stride) {
    const int b = i / P2;
    const float* op = obj + (size_t)i * 3;
    float px = op[0], py = op[1], pz = op[2];
    int bi0 = keys[i];
    int bi1 = keys[(size_t)B * P2 + i];
    float os[2];
    {
      const float* v = recon_xyz + (size_t)(b * P1 + bi0) * 3;
      float dx = px - v[0], dy = py - v[1], dz = pz - v[2];
      float d2 = fmaf(dx, dx, fmaf(dy, dy, dz * dz));
      float4 nb = nrm[(size_t)b * P1 + bi0];
      float dt = nb.x * dx + nb.y * dy + nb.z * dz;
      float sg = (dt > 0.f) ? 1.f : ((dt < 0.f) ? -1.f : 0.f);
      os[0] = sqrtf(d2) * sg;
    }
    {
      const float* v = hand_xyz + (size_t)(b * P1 + bi1) * 3;
      float dx = px - v[0], dy = py - v[1], dz = pz - v[2];
      float d2 = fmaf(dx, dx, fmaf(dy, dy, dz * dz));
      float4 nb = nrm[(size_t)(B + b) * P1 + bi1];
      float dt = nb.x * dx + nb.y * dy + nb.z * dz;
      float sg = (dt > 0.f) ? 1.f : ((dt < 0.f) ? -1.f : 0.f);
      os[1] = sqrtf(d2) * sg;
    }
    bool wdist = (os[1] < 0.01f) && (os[1] > -0.005f);
    float w = (os[0] < 0.f) ? 1.5f : (wdist ? 1.f : 0.1f);
    so += fabsf(os[0] - os[1]) * w;
  }
  // h-part: min over chunks, |a - ag| * vw^0.4
  for (int i = gtid; i < B * P1; i += stride) {
    const int p = i % P1;
    float m0 = 3.0e38f, m1 = 3.0e38f;
    #pragma unroll
    for (int c = 0; c < NCH_H2O; ++c) {
      m0 = fminf(m0, ws[HP_OFF + (size_t)(c*2+0) * B * P1 + i]);
      m1 = fminf(m1, ws[HP_OFF + (size_t)(c*2+1) * B * P1 + i]);
    }
    m0 = fmaxf(m0, 0.f); m1 = fmaxf(m1, 0.f);
    sh += fabsf(sqrtf(m0) - sqrtf(m1)) * powf(vw[p], 0.4f);
  }
  for (int off = 32; off > 0; off >>= 1) {
    sh += __shfl_down(sh, off, 64);
    so += __shfl_down(so, off, 64);
  }
  const int wv = threadIdx.x >> 6;
  if ((threadIdx.x & 63) == 0) { smem[wv*2] = sh; smem[wv*2+1] = so; }
  __syncthreads();
  if (threadIdx.x == 0) {
    float a = 0.f, b = 0.f;
    for (int w = 0; w < 4; ++w) { a += smem[w*2]; b += smem[w*2+1]; }
    ws[R2_OFF + blockIdx.x*2+0] = a;
    ws[R2_OFF + blockIdx.x*2+1] = b;
  }
}

// ---------------- Kernel C: finalize (single wave) ---------------------------
__global__ void kfin(const float* __restrict__ ws, float* __restrict__ out) {
  const int lane = threadIdx.x;
  float sp = 0.f, sr = 0.f, sk = 0.f, sh = 0.f, so = 0.f;
  for (int i = lane; i < RED1_BLKS; i += 64) {
    sp += ws[R1_OFF + i*3+0]; sr += ws[R1_OFF + i*3+1]; sk += ws[R1_OFF + i*3+2];
  }
  for (int i = lane; i < RED2_BLKS; i += 64) {
    sh += ws[R2_OFF + i*2+0]; so += ws[R2_OFF + i*2+1];
  }
  for (int off = 32; off > 0; off >>= 1) {
    sp += __shfl_down(sp, off, 64);
    sr += __shfl_down(sr, off, 64);
    sk += __shfl_down(sk, off, 64);
    sh += __shfl_down(sh, off, 64);
    so += __shfl_down(so, off, 64);
  }
  if (lane == 0) {
    float param_loss = sp / (float)B;
    float recon_loss = sr / (float)B;
    float KLD = -0.5f * sk / (float)B;
    float cvae = recon_loss + KLD;
    float loss_h = 35.f * (1.f - 0.005f) * sh / (float)(B * P1);
    float loss_o = 30.f * (1.f - 0.005f) * so / (float)(B * P2);
    float ho = loss_h + loss_o;
    out[0] = cvae + 0.1f * param_loss + 10.f * ho;
    out[1] = param_loss;
    out[2] = ho;
    out[3] = recon_loss;
    out[4] = KLD;
  }
}

extern "C" void kernel_launch(void* const* d_in, const int* in_sizes, int n_in,
                              void* d_out, int out_size, void* d_ws, size_t ws_size,
                              hipStream_t stream) {
  const float* recon_x   = (const float*)d_in[0];
  const float* x         = (const float*)d_in[1];
  const float* mu        = (const float*)d_in[2];
  const float* logvar    = (const float*)d_in[3];
  const float* recon_xyz = (const float*)d_in[4];
  const float* hand_xyz  = (const float*)d_in[5];
  const int*   faces     = (const int*)d_in[6];
  const float* obj       = (const float*)d_in[7];
  const float* vw        = (const float*)d_in[8];
  float* ws = (float*)d_ws;
  float* out = (float*)d_out;

  kmega<<<dim3(NB_TOT), 256, 0, stream>>>(recon_x, x, mu, logvar,
                                          recon_xyz, hand_xyz, faces, obj, ws);
  kred2<<<dim3(RED2_BLKS), 256, 0, stream>>>(recon_xyz, hand_xyz, obj, vw, ws);
  kfin<<<1, 64, 0, stream>>>(ws, out);
}